// Round 1
// baseline (643.034 us; speedup 1.0000x reference)
//
#include <hip/hip_runtime.h>

#define NF 128

// ---------------- edge scatter: h0[dst] += x[src], wave-per-edge ----------------
__global__ void edge_scatter_kernel(const int* __restrict__ ei, const float* __restrict__ x,
                                    float* __restrict__ h0, int n_edges) {
    int gtid = blockIdx.x * blockDim.x + threadIdx.x;
    int wid  = gtid >> 6;
    int lane = threadIdx.x & 63;
    int nw   = (gridDim.x * blockDim.x) >> 6;
    const int* srcs = ei;
    const int* dsts = ei + n_edges;
    for (int e = wid; e < n_edges; e += nw) {
        int s = srcs[e];
        int d = dsts[e];
        float v0 = x[s * NF + lane];
        float v1 = x[s * NF + 64 + lane];
        atomicAdd(&h0[d * NF + lane], v0);
        atomicAdd(&h0[d * NF + 64 + lane], v1);
    }
}

// ---------------- power iteration: inv_sigma for W1 (block 0) and W2 (block 1) ----
// sigma = ||W v||^2 / (||W v|| + 1e-12), v = W^T u / (||W^T u|| + 1e-12)
__global__ void power_iter_kernel(const float* __restrict__ W1, const float* __restrict__ u1,
                                  const float* __restrict__ W2, const float* __restrict__ u2,
                                  float* __restrict__ inv_sigma, float* __restrict__ colsum,
                                  float* __restrict__ colsumsq) {
    const float* W = blockIdx.x ? W2 : W1;
    const float* u = blockIdx.x ? u2 : u1;
    __shared__ float vv[128];
    __shared__ float red[128];
    int tid = threadIdx.x;   // 128 threads
    if (blockIdx.x == 0) { colsum[tid] = 0.f; colsumsq[tid] = 0.f; }

    // v = W^T u  (thread tid computes column tid)
    float acc = 0.f;
    for (int j = 0; j < 128; ++j) acc = fmaf(W[j * 128 + tid], u[j], acc);
    red[tid] = acc * acc;
    __syncthreads();
    for (int s = 64; s > 0; s >>= 1) {
        if (tid < s) red[tid] += red[tid + s];
        __syncthreads();
    }
    float nv = sqrtf(red[0]) + 1e-12f;
    vv[tid] = acc / nv;
    __syncthreads();

    // t = W v  (thread tid computes row tid)
    float t = 0.f;
    for (int k = 0; k < 128; ++k) t = fmaf(W[tid * 128 + k], vv[k], t);
    red[tid] = t * t;
    __syncthreads();
    for (int s = 64; s > 0; s >>= 1) {
        if (tid < s) red[tid] += red[tid + s];
        __syncthreads();
    }
    if (tid == 0) {
        float tt = red[0];
        float sigma = tt / (sqrtf(tt) + 1e-12f);
        inv_sigma[blockIdx.x] = 1.0f / sigma;
    }
}

// ---------------- 128-wide GEMM: O = act(H @ (s*W)^T + bias), wave-per-row ------
// W staged in LDS with +1 pad (stride-129 -> 2-way bank alias, free).
template <bool RELU>
__global__ void gemm128_kernel(const float* __restrict__ H, const float* __restrict__ Wg,
                               const float* __restrict__ bias, const float* __restrict__ scale_ptr,
                               float* __restrict__ O, int n_rows) {
    __shared__ float Wl[128][129];
    float s = scale_ptr ? scale_ptr[0] : 1.0f;
    for (int i = threadIdx.x; i < 128 * 128; i += blockDim.x) {
        Wl[i >> 7][i & 127] = Wg[i] * s;
    }
    __syncthreads();

    int lane = threadIdx.x & 63;
    int wib  = threadIdx.x >> 6;
    int wpb  = blockDim.x >> 6;
    int gw   = blockIdx.x * wpb + wib;
    int nw   = gridDim.x * wpb;
    float b0 = bias[lane];
    float b1 = bias[lane + 64];

    for (int r = gw; r < n_rows; r += nw) {
        const float4* hrow = (const float4*)(H + (size_t)r * NF);
        float a0 = 0.f, a1 = 0.f;
#pragma unroll
        for (int k4 = 0; k4 < 32; ++k4) {
            float4 h = hrow[k4];   // same addr across lanes -> broadcast, L2-hot
            int k = k4 * 4;
            a0 = fmaf(h.x, Wl[lane][k + 0], a0);
            a0 = fmaf(h.y, Wl[lane][k + 1], a0);
            a0 = fmaf(h.z, Wl[lane][k + 2], a0);
            a0 = fmaf(h.w, Wl[lane][k + 3], a0);
            a1 = fmaf(h.x, Wl[lane + 64][k + 0], a1);
            a1 = fmaf(h.y, Wl[lane + 64][k + 1], a1);
            a1 = fmaf(h.z, Wl[lane + 64][k + 2], a1);
            a1 = fmaf(h.w, Wl[lane + 64][k + 3], a1);
        }
        a0 += b0; a1 += b1;
        if (RELU) { a0 = fmaxf(a0, 0.f); a1 = fmaxf(a1, 0.f); }
        O[(size_t)r * NF + lane]      = a0;
        O[(size_t)r * NF + 64 + lane] = a1;
    }
}

// ---------------- BN column stats over h1 ----------------
__global__ void bn_stats_kernel(const float* __restrict__ h1, float* __restrict__ colsum,
                                float* __restrict__ colsumsq, int n_rows) {
    int c   = threadIdx.x & 127;
    int sub = threadIdx.x >> 7;  // 0..1 for 256 threads
    int stride = gridDim.x * 2;
    float s = 0.f, s2 = 0.f;
    for (int r = blockIdx.x * 2 + sub; r < n_rows; r += stride) {
        float v = h1[(size_t)r * NF + c];
        s += v;
        s2 = fmaf(v, v, s2);
    }
    atomicAdd(&colsum[c], s);
    atomicAdd(&colsumsq[c], s2);
}

// ---------------- fold BN affine into W2', b2' ----------------
__global__ void fold_kernel(const float* __restrict__ W2, const float* __restrict__ b2,
                            const float* __restrict__ gamma, const float* __restrict__ beta,
                            const float* __restrict__ colsum, const float* __restrict__ colsumsq,
                            const float* __restrict__ inv_sigma, float* __restrict__ W2p,
                            float* __restrict__ b2p, float inv_n) {
    __shared__ float a[128], cc[128];
    int tid = threadIdx.x;  // 128 threads
    float mu  = colsum[tid] * inv_n;
    float var = colsumsq[tid] * inv_n - mu * mu;
    float ai  = gamma[tid] / sqrtf(var + 1e-5f);
    a[tid]  = ai;
    cc[tid] = beta[tid] - ai * mu;
    __syncthreads();
    float is2  = inv_sigma[1];
    float bacc = b2[tid];
    for (int k = 0; k < 128; ++k) {
        float w = W2[tid * 128 + k] * is2;
        W2p[tid * 128 + k] = w * a[k];
        bacc = fmaf(w, cc[k], bacc);
    }
    b2p[tid] = bacc;
}

extern "C" void kernel_launch(void* const* d_in, const int* in_sizes, int n_in,
                              void* d_out, int out_size, void* d_ws, size_t ws_size,
                              hipStream_t stream) {
    const float* x     = (const float*)d_in[0];
    const int*   ei    = (const int*)d_in[1];
    const float* W1    = (const float*)d_in[2];
    const float* b1    = (const float*)d_in[3];
    const float* u1    = (const float*)d_in[4];
    const float* gamma = (const float*)d_in[5];
    const float* beta  = (const float*)d_in[6];
    const float* W2    = (const float*)d_in[7];
    const float* b2    = (const float*)d_in[8];
    const float* u2    = (const float*)d_in[9];
    float* out = (float*)d_out;

    int n_nodes = in_sizes[0] / NF;
    int n_edges = in_sizes[1] / 2;

    float* ws        = (float*)d_ws;
    float* h0        = ws;                                  // n_nodes*128
    float* inv_sigma = ws + (size_t)n_nodes * NF;           // 2 (padded to 4)
    float* colsum    = inv_sigma + 4;                       // 128
    float* colsumsq  = colsum + 128;                        // 128
    float* W2p       = colsumsq + 128;                      // 128*128
    float* b2p       = W2p + 128 * 128;                     // 128

    // h0 = x  (GIN eps=0: h = x + agg)
    hipMemcpyAsync(h0, x, (size_t)n_nodes * NF * sizeof(float),
                   hipMemcpyDeviceToDevice, stream);

    // h0[dst] += x[src]
    edge_scatter_kernel<<<2048, 256, 0, stream>>>(ei, x, h0, n_edges);

    // inv_sigma[0], inv_sigma[1]; zeroes colsum/colsumsq
    power_iter_kernel<<<2, 128, 0, stream>>>(W1, u1, W2, u2, inv_sigma, colsum, colsumsq);

    // h1 = relu(h0 @ (W1/sigma1)^T + b1)  -> stored in d_out
    gemm128_kernel<true><<<640, 256, 0, stream>>>(h0, W1, b1, inv_sigma, out, n_nodes);

    // column sums / sumsq of h1
    bn_stats_kernel<<<128, 256, 0, stream>>>(out, colsum, colsumsq, n_nodes);

    // fold BN into W2', b2'
    fold_kernel<<<1, 128, 0, stream>>>(W2, b2, gamma, beta, colsum, colsumsq,
                                       inv_sigma, W2p, b2p, 1.0f / (float)n_nodes);

    // out = h1 @ W2'^T + b2'   (in-place: each wave reads only its own row)
    gemm128_kernel<false><<<640, 256, 0, stream>>>(out, W2p, b2p, nullptr, out, n_nodes);
}

// Round 2
// 441.001 us; speedup vs baseline: 1.4581x; 1.4581x over previous
//
#include <hip/hip_runtime.h>

#define NF 128

// ================= CSR build =================
__global__ void hist_kernel(const int* __restrict__ dst, int* __restrict__ cnt, int n_edges) {
    int i = blockIdx.x * blockDim.x + threadIdx.x;
    int stride = gridDim.x * blockDim.x;
    for (int e = i; e < n_edges; e += stride) atomicAdd(&cnt[dst[e]], 1);
}

__global__ void scan_kernel(const int* __restrict__ cnt, int* __restrict__ offsets, int n) {
    __shared__ int sc[1024];
    int tid = threadIdx.x;
    int C = (n + 1023) >> 10;
    int begin = tid * C;
    int endi = min(begin + C, n);
    int s = 0;
    for (int i = begin; i < endi; ++i) s += cnt[i];
    sc[tid] = s;
    __syncthreads();
    for (int off = 1; off < 1024; off <<= 1) {
        int v = (tid >= off) ? sc[tid - off] : 0;
        __syncthreads();
        sc[tid] += v;
        __syncthreads();
    }
    int base = sc[tid] - s;  // exclusive prefix
    for (int i = begin; i < endi; ++i) { offsets[i] = base; base += cnt[i]; }
    if (tid == 1023) offsets[n] = sc[1023];
}

__global__ void fill_kernel(const int* __restrict__ src, const int* __restrict__ dst,
                            const int* __restrict__ offsets, int* __restrict__ cur,
                            int* __restrict__ bucket, int n_edges) {
    int i = blockIdx.x * blockDim.x + threadIdx.x;
    int stride = gridDim.x * blockDim.x;
    for (int e = i; e < n_edges; e += stride) {
        int d = dst[e];
        int p = offsets[d] + atomicAdd(&cur[d], 1);
        bucket[p] = src[e];
    }
}

// wave-per-node: h0[n] = x[n] + sum_{src in bucket[offsets[n]:offsets[n+1]]} x[src]
__global__ void gather_kernel(const float* __restrict__ x, const int* __restrict__ offsets,
                              const int* __restrict__ bucket, float* __restrict__ h0, int n_nodes) {
    int gw = (blockIdx.x * blockDim.x + threadIdx.x) >> 6;
    int lane = threadIdx.x & 63;
    if (gw >= n_nodes) return;
    const float2* x2 = (const float2*)x;
    float2 acc = x2[(size_t)gw * 64 + lane];
    int start = offsets[gw], end = offsets[gw + 1];
    for (int j = start; j < end; ++j) {
        int s = bucket[j];  // wave-uniform, L1-hot (sequential)
        float2 v = x2[(size_t)s * 64 + lane];
        acc.x += v.x;
        acc.y += v.y;
    }
    ((float2*)h0)[(size_t)gw * 64 + lane] = acc;
}

// ================= fallback: atomic scatter (if ws too small for CSR) =================
__global__ void edge_scatter_kernel(const int* __restrict__ ei, const float* __restrict__ x,
                                    float* __restrict__ h0, int n_edges) {
    int gtid = blockIdx.x * blockDim.x + threadIdx.x;
    int wid = gtid >> 6;
    int lane = threadIdx.x & 63;
    int nw = (gridDim.x * blockDim.x) >> 6;
    const int* srcs = ei;
    const int* dsts = ei + n_edges;
    for (int e = wid; e < n_edges; e += nw) {
        int s = srcs[e];
        int d = dsts[e];
        atomicAdd(&h0[d * NF + lane], x[s * NF + lane]);
        atomicAdd(&h0[d * NF + 64 + lane], x[s * NF + 64 + lane]);
    }
}

// ================= power iteration: inv_sigma[b] for W1 (b=0), W2 (b=1) =================
// sigma = ||Wv||^2/(||Wv||+1e-12), v = W^T u/(||W^T u||+1e-12); inv_sigma = (sqrt(tt)+1e-12)/tt
__global__ void power_iter_kernel(const float* __restrict__ W1, const float* __restrict__ u1,
                                  const float* __restrict__ W2, const float* __restrict__ u2,
                                  float* __restrict__ inv_sigma) {
    const float* W = blockIdx.x ? W2 : W1;
    const float* u = blockIdx.x ? u2 : u1;
    __shared__ float Wl[128][129];
    __shared__ float us[128], vv[128], part[4][128], red[128];
    int tid = threadIdx.x;  // 512 threads

    const float4* W4 = (const float4*)W;
    for (int j = tid; j < 4096; j += 512) {
        float4 w = W4[j];
        int r = j >> 5, c0 = (j & 31) << 2;
        Wl[r][c0] = w.x; Wl[r][c0 + 1] = w.y; Wl[r][c0 + 2] = w.z; Wl[r][c0 + 3] = w.w;
    }
    if (tid < 128) us[tid] = u[tid];
    __syncthreads();

    int c = tid & 127, sl = tid >> 7;
    // v = W^T u (K-sliced over 4 groups)
    float acc = 0.f;
#pragma unroll
    for (int j = 0; j < 32; ++j) acc = fmaf(Wl[sl * 32 + j][c], us[sl * 32 + j], acc);
    part[sl][c] = acc;
    __syncthreads();
    if (tid < 128) {
        float v = part[0][tid] + part[1][tid] + part[2][tid] + part[3][tid];
        vv[tid] = v;
        red[tid] = v * v;
    }
    __syncthreads();
    for (int s = 64; s > 0; s >>= 1) { if (tid < s) red[tid] += red[tid + s]; __syncthreads(); }
    float nv = sqrtf(red[0]) + 1e-12f;
    __syncthreads();
    if (tid < 128) vv[tid] = vv[tid] / nv;
    __syncthreads();

    // t = W v
    float t = 0.f;
#pragma unroll
    for (int k = 0; k < 32; ++k) t = fmaf(Wl[c][sl * 32 + k], vv[sl * 32 + k], t);
    part[sl][c] = t;
    __syncthreads();
    if (tid < 128) {
        float tv = part[0][tid] + part[1][tid] + part[2][tid] + part[3][tid];
        red[tid] = tv * tv;
    }
    __syncthreads();
    for (int s = 64; s > 0; s >>= 1) { if (tid < s) red[tid] += red[tid + s]; __syncthreads(); }
    if (tid == 0) {
        float tt = red[0];
        inv_sigma[blockIdx.x] = (sqrtf(tt) + 1e-12f) / tt;
    }
}

// ================= 128-wide GEMM: O = act(H @ (s*W)^T + bias), wave-per-row =================
// optional fused BN column stats (sum, sumsq) via per-block LDS reduce + 1 atomic/col/block
template <bool RELU, bool BNACC>
__global__ void gemm128_kernel(const float* __restrict__ H, const float* __restrict__ Wg,
                               const float* __restrict__ bias, const float* __restrict__ scale_ptr,
                               float* __restrict__ O, float* __restrict__ colsum,
                               float* __restrict__ colsumsq, int n_rows) {
    __shared__ float Wl[128][129];
    __shared__ float sS[4][128];
    __shared__ float sQ[4][128];
    float s = scale_ptr ? scale_ptr[0] : 1.0f;
    const float4* Wg4 = (const float4*)Wg;
    for (int j = threadIdx.x; j < 4096; j += blockDim.x) {
        float4 w = Wg4[j];
        int r = j >> 5, c0 = (j & 31) << 2;
        Wl[r][c0] = w.x * s; Wl[r][c0 + 1] = w.y * s;
        Wl[r][c0 + 2] = w.z * s; Wl[r][c0 + 3] = w.w * s;
    }
    __syncthreads();

    int lane = threadIdx.x & 63;
    int wib = threadIdx.x >> 6;
    int wpb = blockDim.x >> 6;
    int gw = blockIdx.x * wpb + wib;
    int nw = gridDim.x * wpb;
    float b0 = bias[lane];
    float b1 = bias[lane + 64];
    float s0 = 0.f, s1 = 0.f, q0 = 0.f, q1 = 0.f;

    for (int r = gw; r < n_rows; r += nw) {
        const float4* hrow = (const float4*)(H + (size_t)r * NF);
        float a0 = 0.f, a1 = 0.f;
#pragma unroll
        for (int k4 = 0; k4 < 32; ++k4) {
            float4 h = hrow[k4];  // broadcast across lanes
            int k = k4 * 4;
            a0 = fmaf(h.x, Wl[lane][k + 0], a0);
            a0 = fmaf(h.y, Wl[lane][k + 1], a0);
            a0 = fmaf(h.z, Wl[lane][k + 2], a0);
            a0 = fmaf(h.w, Wl[lane][k + 3], a0);
            a1 = fmaf(h.x, Wl[lane + 64][k + 0], a1);
            a1 = fmaf(h.y, Wl[lane + 64][k + 1], a1);
            a1 = fmaf(h.z, Wl[lane + 64][k + 2], a1);
            a1 = fmaf(h.w, Wl[lane + 64][k + 3], a1);
        }
        a0 += b0; a1 += b1;
        if (RELU) { a0 = fmaxf(a0, 0.f); a1 = fmaxf(a1, 0.f); }
        if (BNACC) {
            s0 += a0; s1 += a1;
            q0 = fmaf(a0, a0, q0); q1 = fmaf(a1, a1, q1);
        }
        O[(size_t)r * NF + lane] = a0;
        O[(size_t)r * NF + 64 + lane] = a1;
    }

    if (BNACC) {
        sS[wib][lane] = s0; sS[wib][lane + 64] = s1;
        sQ[wib][lane] = q0; sQ[wib][lane + 64] = q1;
        __syncthreads();
        if (threadIdx.x < 128) {
            int cI = threadIdx.x;
            float ts = sS[0][cI] + sS[1][cI] + sS[2][cI] + sS[3][cI];
            float tq = sQ[0][cI] + sQ[1][cI] + sQ[2][cI] + sQ[3][cI];
            atomicAdd(&colsum[cI], ts);
            atomicAdd(&colsumsq[cI], tq);
        }
    }
}

// ================= fold BN affine into W2', b2' (block per output row) =================
__global__ void fold_kernel(const float* __restrict__ W2, const float* __restrict__ b2,
                            const float* __restrict__ gamma, const float* __restrict__ beta,
                            const float* __restrict__ colsum, const float* __restrict__ colsumsq,
                            const float* __restrict__ inv_sigma, float* __restrict__ W2p,
                            float* __restrict__ b2p, float inv_n) {
    __shared__ float a[128], cc[128], red[128];
    int k = threadIdx.x;  // 128 threads
    int j = blockIdx.x;   // 128 blocks
    float mu = colsum[k] * inv_n;
    float var = colsumsq[k] * inv_n - mu * mu;
    float ai = gamma[k] / sqrtf(var + 1e-5f);
    a[k] = ai;
    cc[k] = beta[k] - ai * mu;
    __syncthreads();
    float is2 = inv_sigma[1];
    float w = W2[j * 128 + k] * is2;
    W2p[j * 128 + k] = w * a[k];
    red[k] = w * cc[k];
    __syncthreads();
    for (int s = 64; s > 0; s >>= 1) { if (k < s) red[k] += red[k + s]; __syncthreads(); }
    if (k == 0) b2p[j] = b2[j] + red[0];
}

extern "C" void kernel_launch(void* const* d_in, const int* in_sizes, int n_in,
                              void* d_out, int out_size, void* d_ws, size_t ws_size,
                              hipStream_t stream) {
    const float* x     = (const float*)d_in[0];
    const int*   ei    = (const int*)d_in[1];
    const float* W1    = (const float*)d_in[2];
    const float* b1    = (const float*)d_in[3];
    const float* u1    = (const float*)d_in[4];
    const float* gamma = (const float*)d_in[5];
    const float* beta  = (const float*)d_in[6];
    const float* W2    = (const float*)d_in[7];
    const float* b2    = (const float*)d_in[8];
    const float* u2    = (const float*)d_in[9];
    float* out = (float*)d_out;

    int n_nodes = in_sizes[0] / NF;
    int n_edges = in_sizes[1] / 2;

    float* ws        = (float*)d_ws;
    float* h0        = ws;                         // n_nodes*128
    float* inv_sigma = ws + (size_t)n_nodes * NF;  // 4
    float* colsum    = inv_sigma + 4;              // 128
    float* colsumsq  = colsum + 128;               // 128
    float* W2p       = colsumsq + 128;             // 128*128
    float* b2p       = W2p + 128 * 128;            // 128
    int*   cnt       = (int*)(b2p + 128);          // n_nodes
    int*   offsets   = cnt + n_nodes;              // n_nodes+1
    int*   bucket    = offsets + n_nodes + 1;      // n_edges

    size_t float_bytes = ((size_t)n_nodes * NF + 4 + 256 + 128 * 128 + 128) * sizeof(float);
    size_t csr_bytes   = ((size_t)2 * n_nodes + 1 + n_edges) * sizeof(int);
    bool use_csr = ws_size >= float_bytes + csr_bytes;

    // colsum/colsumsq zero (contiguous 256 floats)
    hipMemsetAsync(colsum, 0, 256 * sizeof(float), stream);

    power_iter_kernel<<<2, 512, 0, stream>>>(W1, u1, W2, u2, inv_sigma);

    if (use_csr) {
        hipMemsetAsync(cnt, 0, (size_t)n_nodes * sizeof(int), stream);
        hist_kernel<<<1024, 256, 0, stream>>>(ei + n_edges, cnt, n_edges);
        scan_kernel<<<1, 1024, 0, stream>>>(cnt, offsets, n_nodes);
        hipMemsetAsync(cnt, 0, (size_t)n_nodes * sizeof(int), stream);
        fill_kernel<<<1024, 256, 0, stream>>>(ei, ei + n_edges, offsets, cnt, bucket, n_edges);
        int gblocks = (n_nodes * 64 + 255) / 256;
        gather_kernel<<<gblocks, 256, 0, stream>>>(x, offsets, bucket, h0, n_nodes);
    } else {
        hipMemcpyAsync(h0, x, (size_t)n_nodes * NF * sizeof(float),
                       hipMemcpyDeviceToDevice, stream);
        edge_scatter_kernel<<<2048, 256, 0, stream>>>(ei, x, h0, n_edges);
    }

    // h1 = relu(h0 @ (W1/sigma1)^T + b1) -> d_out, fused BN col stats
    gemm128_kernel<true, true><<<512, 256, 0, stream>>>(h0, W1, b1, inv_sigma, out,
                                                        colsum, colsumsq, n_nodes);

    fold_kernel<<<128, 128, 0, stream>>>(W2, b2, gamma, beta, colsum, colsumsq,
                                         inv_sigma, W2p, b2p, 1.0f / (float)n_nodes);

    // out = h1 @ W2'^T + b2'  (in-place: each wave reads only its own row)
    gemm128_kernel<false, false><<<512, 256, 0, stream>>>(out, W2p, b2p, nullptr, out,
                                                          nullptr, nullptr, n_nodes);
}

// Round 3
// 246.147 us; speedup vs baseline: 2.6124x; 1.7916x over previous
//
#include <hip/hip_runtime.h>

#define NF 128

// ================= CSR build =================
__global__ void hist_kernel(const int* __restrict__ dst, int* __restrict__ cnt, int n_edges) {
    int i = blockIdx.x * blockDim.x + threadIdx.x;
    int stride = gridDim.x * blockDim.x;
    for (int e = i; e < n_edges; e += stride) atomicAdd(&cnt[dst[e]], 1);
}

__global__ void scan_kernel(const int* __restrict__ cnt, int* __restrict__ offsets, int n) {
    __shared__ int sc[1024];
    int tid = threadIdx.x;
    int C = (n + 1023) >> 10;
    int begin = tid * C;
    int endi = min(begin + C, n);
    int s = 0;
    for (int i = begin; i < endi; ++i) s += cnt[i];
    sc[tid] = s;
    __syncthreads();
    for (int off = 1; off < 1024; off <<= 1) {
        int v = (tid >= off) ? sc[tid - off] : 0;
        __syncthreads();
        sc[tid] += v;
        __syncthreads();
    }
    int base = sc[tid] - s;  // exclusive prefix
    for (int i = begin; i < endi; ++i) { offsets[i] = base; base += cnt[i]; }
    if (tid == 1023) offsets[n] = sc[1023];
}

__global__ void fill_kernel(const int* __restrict__ src, const int* __restrict__ dst,
                            const int* __restrict__ offsets, int* __restrict__ cur,
                            int* __restrict__ bucket, int n_edges) {
    int i = blockIdx.x * blockDim.x + threadIdx.x;
    int stride = gridDim.x * blockDim.x;
    for (int e = i; e < n_edges; e += stride) {
        int d = dst[e];
        int p = offsets[d] + atomicAdd(&cur[d], 1);
        bucket[p] = src[e];
    }
}

// wave-per-node: h0[n] = x[n] + sum_{src in bucket[offsets[n]:offsets[n+1]]} x[src]
__global__ void gather_kernel(const float* __restrict__ x, const int* __restrict__ offsets,
                              const int* __restrict__ bucket, float* __restrict__ h0, int n_nodes) {
    int gw = (blockIdx.x * blockDim.x + threadIdx.x) >> 6;
    int lane = threadIdx.x & 63;
    if (gw >= n_nodes) return;
    const float2* x2 = (const float2*)x;
    float2 acc = x2[(size_t)gw * 64 + lane];
    int start = offsets[gw], end = offsets[gw + 1];
    for (int j = start; j < end; ++j) {
        int s = bucket[j];
        float2 v = x2[(size_t)s * 64 + lane];
        acc.x += v.x;
        acc.y += v.y;
    }
    ((float2*)h0)[(size_t)gw * 64 + lane] = acc;
}

// ================= fallback: atomic scatter =================
__global__ void edge_scatter_kernel(const int* __restrict__ ei, const float* __restrict__ x,
                                    float* __restrict__ h0, int n_edges) {
    int gtid = blockIdx.x * blockDim.x + threadIdx.x;
    int wid = gtid >> 6;
    int lane = threadIdx.x & 63;
    int nw = (gridDim.x * blockDim.x) >> 6;
    const int* srcs = ei;
    const int* dsts = ei + n_edges;
    for (int e = wid; e < n_edges; e += nw) {
        int s = srcs[e];
        int d = dsts[e];
        atomicAdd(&h0[d * NF + lane], x[s * NF + lane]);
        atomicAdd(&h0[d * NF + 64 + lane], x[s * NF + 64 + lane]);
    }
}

// ================= power iteration =================
__global__ void power_iter_kernel(const float* __restrict__ W1, const float* __restrict__ u1,
                                  const float* __restrict__ W2, const float* __restrict__ u2,
                                  float* __restrict__ inv_sigma) {
    const float* W = blockIdx.x ? W2 : W1;
    const float* u = blockIdx.x ? u2 : u1;
    __shared__ float Wl[128][129];
    __shared__ float us[128], vv[128], part[4][128], red[128];
    int tid = threadIdx.x;  // 512 threads

    const float4* W4 = (const float4*)W;
    for (int j = tid; j < 4096; j += 512) {
        float4 w = W4[j];
        int r = j >> 5, c0 = (j & 31) << 2;
        Wl[r][c0] = w.x; Wl[r][c0 + 1] = w.y; Wl[r][c0 + 2] = w.z; Wl[r][c0 + 3] = w.w;
    }
    if (tid < 128) us[tid] = u[tid];
    __syncthreads();

    int c = tid & 127, sl = tid >> 7;
    float acc = 0.f;
#pragma unroll
    for (int j = 0; j < 32; ++j) acc = fmaf(Wl[sl * 32 + j][c], us[sl * 32 + j], acc);
    part[sl][c] = acc;
    __syncthreads();
    if (tid < 128) {
        float v = part[0][tid] + part[1][tid] + part[2][tid] + part[3][tid];
        vv[tid] = v;
        red[tid] = v * v;
    }
    __syncthreads();
    for (int s = 64; s > 0; s >>= 1) { if (tid < s) red[tid] += red[tid + s]; __syncthreads(); }
    float nv = sqrtf(red[0]) + 1e-12f;
    __syncthreads();
    if (tid < 128) vv[tid] = vv[tid] / nv;
    __syncthreads();

    float t = 0.f;
#pragma unroll
    for (int k = 0; k < 32; ++k) t = fmaf(Wl[c][sl * 32 + k], vv[sl * 32 + k], t);
    part[sl][c] = t;
    __syncthreads();
    if (tid < 128) {
        float tv = part[0][tid] + part[1][tid] + part[2][tid] + part[3][tid];
        red[tid] = tv * tv;
    }
    __syncthreads();
    for (int s = 64; s > 0; s >>= 1) { if (tid < s) red[tid] += red[tid + s]; __syncthreads(); }
    if (tid == 0) {
        float tt = red[0];
        inv_sigma[blockIdx.x] = (sqrtf(tt) + 1e-12f) / tt;
    }
}

// ================= W1t[k][j] = W1[j][k] * inv_sigma[0] =================
__global__ void transpose_scale_kernel(const float* __restrict__ W, const float* __restrict__ inv_sigma,
                                       float* __restrict__ Wt) {
    int j = blockIdx.x, k = threadIdx.x;
    Wt[k * 128 + j] = W[j * 128 + k] * inv_sigma[0];
}

// ================= tiled GEMM: O[r][c] = act(sum_k H[r][k]*Wt[k][c] + bias[c]) ========
// BM=64, BN=128, 256 threads; thread (ty,tx): rows ty*8..+7, cols tx*4..+3 (8x4 regs).
// Wt is PRE-TRANSPOSED [k][c] in global -> all LDS stages linear, reads conflict-free:
//   H reads broadcast (2 addrs/wave), W reads consecutive 16B granules across tx.
template <bool RELU, bool BNACC>
__global__ __launch_bounds__(256, 1) void gemm_tiled_kernel(
        const float* __restrict__ H, const float* __restrict__ Wt,
        const float* __restrict__ bias, float* __restrict__ O,
        float* __restrict__ colsum, float* __restrict__ colsumsq, int n_rows) {
    __shared__ float Hl[64][128];    // 32 KB, natural layout (broadcast reads)
    __shared__ float Wl[128][132];   // 66 KB, [k][c], stride 132 keeps rows 16B-aligned
    int tid = threadIdx.x;
    int m0 = blockIdx.x * 64;

    // stage Wt (linear, coalesced, conflict-free)
    const float4* Wt4 = (const float4*)Wt;
    for (int j = tid; j < 4096; j += 256) {
        int k = j >> 5, c4 = (j & 31) << 2;
        float4 w = Wt4[j];
        *(float4*)&Wl[k][c4] = w;
    }
    // stage H tile (guard tail rows with zeros)
    const float4* H4 = (const float4*)H;
    for (int j = tid; j < 2048; j += 256) {
        int r = j >> 5, k4 = j & 31;
        int gr = m0 + r;
        float4 h = (gr < n_rows) ? H4[(size_t)gr * 32 + k4] : make_float4(0.f, 0.f, 0.f, 0.f);
        *(float4*)&Hl[r][k4 << 2] = h;
    }
    __syncthreads();

    int tx = tid & 31, ty = tid >> 5;
    int rb = ty * 8, cb = tx * 4;
    float acc[8][4] = {};

    for (int k = 0; k < 128; k += 4) {
        float wv[4][4];
#pragma unroll
        for (int kk = 0; kk < 4; ++kk) {
            float4 t = *(const float4*)&Wl[k + kk][cb];
            wv[kk][0] = t.x; wv[kk][1] = t.y; wv[kk][2] = t.z; wv[kk][3] = t.w;
        }
#pragma unroll
        for (int i = 0; i < 8; ++i) {
            float4 h = *(const float4*)&Hl[rb + i][k];
            float hf[4] = {h.x, h.y, h.z, h.w};
#pragma unroll
            for (int kk = 0; kk < 4; ++kk)
#pragma unroll
                for (int j = 0; j < 4; ++j)
                    acc[i][j] = fmaf(hf[kk], wv[kk][j], acc[i][j]);
        }
    }

    float bv[4];
#pragma unroll
    for (int j = 0; j < 4; ++j) bv[j] = bias[cb + j];

    float s[4] = {0.f, 0.f, 0.f, 0.f}, q[4] = {0.f, 0.f, 0.f, 0.f};
#pragma unroll
    for (int i = 0; i < 8; ++i) {
        int gr = m0 + rb + i;
        if (gr < n_rows) {
            float o[4];
#pragma unroll
            for (int j = 0; j < 4; ++j) {
                float v = acc[i][j] + bv[j];
                if (RELU) v = fmaxf(v, 0.f);
                o[j] = v;
                if (BNACC) { s[j] += v; q[j] = fmaf(v, v, q[j]); }
            }
            float4 ov = make_float4(o[0], o[1], o[2], o[3]);
            *(float4*)&O[(size_t)gr * NF + cb] = ov;
        }
    }

    if (BNACC) {
        __syncthreads();  // done reading Hl; reuse as reduce scratch
        float* sS = &Hl[0][0];    // [8][128]
        float* sQ = &Hl[16][0];   // [8][128]
#pragma unroll
        for (int j = 0; j < 4; ++j) {
            sS[ty * 128 + cb + j] = s[j];
            sQ[ty * 128 + cb + j] = q[j];
        }
        __syncthreads();
        if (tid < 128) {
            float ts = 0.f, tq = 0.f;
#pragma unroll
            for (int g = 0; g < 8; ++g) {
                ts += sS[g * 128 + tid];
                tq += sQ[g * 128 + tid];
            }
            atomicAdd(&colsum[tid], ts);
            atomicAdd(&colsumsq[tid], tq);
        }
    }
}

// ================= fold BN into W2', emit TRANSPOSED W2pt[k][j], b2p =================
__global__ void fold_kernel(const float* __restrict__ W2, const float* __restrict__ b2,
                            const float* __restrict__ gamma, const float* __restrict__ beta,
                            const float* __restrict__ colsum, const float* __restrict__ colsumsq,
                            const float* __restrict__ inv_sigma, float* __restrict__ W2pt,
                            float* __restrict__ b2p, float inv_n) {
    __shared__ float a[128], cc[128], red[128];
    int k = threadIdx.x;  // 128 threads
    int j = blockIdx.x;   // 128 blocks (output row of W2)
    float mu = colsum[k] * inv_n;
    float var = colsumsq[k] * inv_n - mu * mu;
    float ai = gamma[k] / sqrtf(var + 1e-5f);
    a[k] = ai;
    cc[k] = beta[k] - ai * mu;
    __syncthreads();
    float is2 = inv_sigma[1];
    float w = W2[j * 128 + k] * is2;
    W2pt[k * 128 + j] = w * a[k];    // transposed store
    red[k] = w * cc[k];
    __syncthreads();
    for (int s = 64; s > 0; s >>= 1) { if (k < s) red[k] += red[k + s]; __syncthreads(); }
    if (k == 0) b2p[j] = b2[j] + red[0];
}

extern "C" void kernel_launch(void* const* d_in, const int* in_sizes, int n_in,
                              void* d_out, int out_size, void* d_ws, size_t ws_size,
                              hipStream_t stream) {
    const float* x     = (const float*)d_in[0];
    const int*   ei    = (const int*)d_in[1];
    const float* W1    = (const float*)d_in[2];
    const float* b1    = (const float*)d_in[3];
    const float* u1    = (const float*)d_in[4];
    const float* gamma = (const float*)d_in[5];
    const float* beta  = (const float*)d_in[6];
    const float* W2    = (const float*)d_in[7];
    const float* b2    = (const float*)d_in[8];
    const float* u2    = (const float*)d_in[9];
    float* out = (float*)d_out;

    int n_nodes = in_sizes[0] / NF;
    int n_edges = in_sizes[1] / 2;

    float* ws        = (float*)d_ws;
    float* h0        = ws;                         // n_nodes*128
    float* inv_sigma = ws + (size_t)n_nodes * NF;  // 4
    float* colsum    = inv_sigma + 4;              // 128
    float* colsumsq  = colsum + 128;               // 128
    float* W1t       = colsumsq + 128;             // 128*128
    float* W2pt      = W1t + 128 * 128;            // 128*128
    float* b2p       = W2pt + 128 * 128;           // 128
    int*   cnt       = (int*)(b2p + 128);          // n_nodes
    int*   offsets   = cnt + n_nodes;              // n_nodes+1
    int*   bucket    = offsets + n_nodes + 1;      // n_edges

    size_t float_bytes = ((size_t)n_nodes * NF + 4 + 256 + 2 * 128 * 128 + 128) * sizeof(float);
    size_t csr_bytes   = ((size_t)2 * n_nodes + 1 + n_edges) * sizeof(int);
    bool use_csr = ws_size >= float_bytes + csr_bytes;

    hipMemsetAsync(colsum, 0, 256 * sizeof(float), stream);

    power_iter_kernel<<<2, 512, 0, stream>>>(W1, u1, W2, u2, inv_sigma);
    transpose_scale_kernel<<<128, 128, 0, stream>>>(W1, inv_sigma, W1t);

    if (use_csr) {
        hipMemsetAsync(cnt, 0, (size_t)n_nodes * sizeof(int), stream);
        hist_kernel<<<1024, 256, 0, stream>>>(ei + n_edges, cnt, n_edges);
        scan_kernel<<<1, 1024, 0, stream>>>(cnt, offsets, n_nodes);
        hipMemsetAsync(cnt, 0, (size_t)n_nodes * sizeof(int), stream);
        fill_kernel<<<1024, 256, 0, stream>>>(ei, ei + n_edges, offsets, cnt, bucket, n_edges);
        int gblocks = (n_nodes * 64 + 255) / 256;
        gather_kernel<<<gblocks, 256, 0, stream>>>(x, offsets, bucket, h0, n_nodes);
    } else {
        hipMemcpyAsync(h0, x, (size_t)n_nodes * NF * sizeof(float),
                       hipMemcpyDeviceToDevice, stream);
        edge_scatter_kernel<<<2048, 256, 0, stream>>>(ei, x, h0, n_edges);
    }

    int gemm_blocks = (n_nodes + 63) / 64;

    // h1 = relu(h0 @ W1sn^T + b1) -> d_out, fused BN col stats
    gemm_tiled_kernel<true, true><<<gemm_blocks, 256, 0, stream>>>(
        h0, W1t, b1, out, colsum, colsumsq, n_nodes);

    fold_kernel<<<128, 128, 0, stream>>>(W2, b2, gamma, beta, colsum, colsumsq,
                                         inv_sigma, W2pt, b2p, 1.0f / (float)n_nodes);

    // out = h1 @ W2p^T + b2p  (in-place: block reads only its own tile rows)
    gemm_tiled_kernel<false, false><<<gemm_blocks, 256, 0, stream>>>(
        out, W2pt, b2p, out, nullptr, nullptr, n_nodes);
}